// Round 6
// baseline (430.879 us; speedup 1.0000x reference)
//
#include <hip/hip_runtime.h>

typedef unsigned short u16;
typedef short bf16x8 __attribute__((ext_vector_type(8)));
typedef float f32x4 __attribute__((ext_vector_type(4)));

#define GLB __attribute__((address_space(1)))
#define LDSAS __attribute__((address_space(3)))

constexpr int S = 2048, D = 4096, NH = 32, NHK = 8, DHD = 128;
constexpr int NQKV = 6144;  // 4096 q + 1024 k + 1024 v

__device__ __forceinline__ u16 f2b(float f) {
    union { float f; unsigned u; } v; v.f = f;
    return (u16)((v.u + 0x7fffu + ((v.u >> 16) & 1u)) >> 16);
}
__device__ __forceinline__ float b2f(u16 b) {
    union { unsigned u; float f; } v; v.u = ((unsigned)b) << 16;
    return v.f;
}
__device__ __forceinline__ void gload16(const void* g, void* l) {
    __builtin_amdgcn_global_load_lds((const GLB unsigned int*)g,
                                     (LDSAS unsigned int*)l, 16, 0, 0);
}
#if __has_builtin(__builtin_amdgcn_exp2f)
__device__ __forceinline__ float exp2fast(float x) { return __builtin_amdgcn_exp2f(x); }
#else
__device__ __forceinline__ float exp2fast(float x) { return __expf(0.6931471805599453f * x); }
#endif

// Accurate sin/cos for large args: reduce to revolutions in [0,1), then v_sin/v_cos.
__device__ __forceinline__ void sincos_big(float ang, float* sn, float* cs) {
#if __has_builtin(__builtin_amdgcn_sinf) && __has_builtin(__builtin_amdgcn_cosf)
    float rev = ang * 0.15915494309189535f;  // 1/(2*pi)
    rev = rev - floorf(rev);                 // [0,1)
    *sn = __builtin_amdgcn_sinf(rev);
    *cs = __builtin_amdgcn_cosf(rev);
#else
    *sn = sinf(ang);
    *cs = cosf(ang);
#endif
}

// ---------------- f32 -> bf16 elementwise (8/thread) ----------------
__global__ __launch_bounds__(256) void cvt_x(const float* __restrict__ in,
                                             u16* __restrict__ out, int n8) {
    int i = blockIdx.x * 256 + threadIdx.x;
    if (i >= n8) return;
    const float4* p = (const float4*)in + (size_t)i * 2;
    float4 a = p[0], b = p[1];
    uint4 o;
    o.x = f2b(a.x) | ((unsigned)f2b(a.y) << 16);
    o.y = f2b(a.z) | ((unsigned)f2b(a.w) << 16);
    o.z = f2b(b.x) | ((unsigned)f2b(b.y) << 16);
    o.w = f2b(b.z) | ((unsigned)f2b(b.w) << 16);
    *(uint4*)(out + (size_t)i * 8) = o;
}

// ---------------- f32 [R][C] -> bf16 [C][R] ----------------
__global__ __launch_bounds__(256) void tconv(const float* __restrict__ in,
                                             u16* __restrict__ out, int R, int C) {
    __shared__ float t[64][65];
    int r0 = blockIdx.y * 64, c0 = blockIdx.x * 64;
    int tx = threadIdx.x & 63, ty = threadIdx.x >> 6;
#pragma unroll
    for (int i = 0; i < 64; i += 4)
        t[ty + i][tx] = in[(size_t)(r0 + ty + i) * C + c0 + tx];
    __syncthreads();
#pragma unroll
    for (int i = 0; i < 64; i += 4)
        out[(size_t)(c0 + ty + i) * R + r0 + tx] = f2b(t[tx][ty + i]);
}

// ---------------- bf16 V (QKV cols 5120..6143) -> Vt [hk][d][s] ----------------
__global__ __launch_bounds__(256) void vtrans(const u16* __restrict__ QKV,
                                              u16* __restrict__ Vt) {
    __shared__ u16 t[64][65];
    int hk = blockIdx.z;
    int s0 = blockIdx.x * 64, d0 = blockIdx.y * 64;
    int tx = threadIdx.x & 63, ty = threadIdx.x >> 6;
#pragma unroll
    for (int i = 0; i < 64; i += 4)
        t[ty + i][tx] = QKV[(size_t)(s0 + ty + i) * NQKV + 5120 + hk * 128 + d0 + tx];
    __syncthreads();
#pragma unroll
    for (int i = 0; i < 64; i += 4)
        Vt[(size_t)hk * (128 * 2048) + (size_t)(d0 + ty + i) * 2048 + s0 + tx] = t[tx][ty + i];
}

// ---------------- RoPE in place, bf16, stride NQKV; scale folded in ----------------
template <int NHEADS>
__global__ __launch_bounds__(256) void rope2(u16* __restrict__ T,
                                             const int* __restrict__ pos, float scale) {
    int idx = blockIdx.x * 256 + threadIdx.x;
    int d = idx & 63;
    int h = (idx >> 6) & (NHEADS - 1);
    int s = idx >> (6 + (NHEADS == 32 ? 5 : 3));
    float p = (float)pos[s];
    float inv = __expf(-(float)d * 0.14391156531310576f);  // 10000^(-d/64)
    float ang = p * inv;
    float sn, cs;
    sincos_big(ang, &sn, &cs);
    size_t base = (size_t)s * NQKV + h * 128 + d;
    float x1 = b2f(T[base]), x2 = b2f(T[base + 64]);
    T[base]      = f2b((x1 * cs - x2 * sn) * scale);
    T[base + 64] = f2b((x2 * cs + x1 * sn) * scale);
}

// ---------------- GEMM v2: 128x256 tile, BK=64, 8 waves, dbuf + counted vmcnt ----------------
// T2 chunk-XOR swizzle (c ^ row&7 on 128B rows), T4 vmcnt(6) prefetch, T5 setprio,
// XCD-bijective block swizzle. C[M][N] = A[M][K](bf16) * Bt[N][K](bf16).
template <bool BF16OUT>
__global__ __launch_bounds__(512, 2) void gemm8(const u16* __restrict__ A,
                                                const u16* __restrict__ Bt,
                                                void* __restrict__ Cout,
                                                int N, int K, int nbx) {
    __shared__ u16 Asm[2][128 * 64];  // 32 KB
    __shared__ u16 Bsm[2][256 * 64];  // 64 KB
    const int nwg = gridDim.x;            // multiple of 8
    const int cpx = nwg >> 3;
    const int b = ((int)blockIdx.x & 7) * cpx + ((int)blockIdx.x >> 3);
    const int by = b / nbx, bx = b - by * nbx;
    const int m0 = by * 128, n0 = bx * 256;
    const int tid = threadIdx.x;
    const int lane = tid & 63;
    const int wave = tid >> 6;
    const int l15 = lane & 15, l4 = lane >> 4;
    const int wm = wave >> 2, wn = wave & 3;  // 2 x 4 waves of 64x64
    f32x4 acc[4][4] = {};

    auto stage = [&](int t, int buf) {
        const int k0 = t * 64;
#pragma unroll
        for (int u = 0; u < 2; ++u) {
            int s = u * 512 + tid;
            int row = s >> 3, cs = (s & 7) ^ (row & 7);
            gload16(A + (size_t)(m0 + row) * K + k0 + cs * 8, &Asm[buf][s * 8]);
        }
#pragma unroll
        for (int u = 0; u < 4; ++u) {
            int s = u * 512 + tid;
            int row = s >> 3, cs = (s & 7) ^ (row & 7);
            gload16(Bt + (size_t)(n0 + row) * K + k0 + cs * 8, &Bsm[buf][s * 8]);
        }
    };

    const int NT = K >> 6;
    stage(0, 0);
#pragma unroll 1
    for (int t = 0; t < NT; ++t) {
        const int c = t & 1;
        if (t + 1 < NT) {
            stage(t + 1, c ^ 1);
            asm volatile("s_waitcnt vmcnt(6)" ::: "memory");  // tile t's 6 loads done
        } else {
            asm volatile("s_waitcnt vmcnt(0)" ::: "memory");
        }
        __builtin_amdgcn_s_barrier();
#pragma unroll
        for (int kk = 0; kk < 2; ++kk) {
            bf16x8 af[4], bf[4];
#pragma unroll
            for (int i = 0; i < 4; ++i) {
                int row = wm * 64 + i * 16 + l15;
                int cc = (kk * 4 + l4) ^ (row & 7);
                af[i] = *(const bf16x8*)(&Asm[c][row * 64 + cc * 8]);
            }
#pragma unroll
            for (int j = 0; j < 4; ++j) {
                int row = wn * 64 + j * 16 + l15;
                int cc = (kk * 4 + l4) ^ (row & 7);
                bf[j] = *(const bf16x8*)(&Bsm[c][row * 64 + cc * 8]);
            }
            __builtin_amdgcn_s_setprio(1);
#pragma unroll
            for (int i = 0; i < 4; ++i)
#pragma unroll
                for (int j = 0; j < 4; ++j)
                    acc[i][j] = __builtin_amdgcn_mfma_f32_16x16x32_bf16(af[i], bf[j], acc[i][j], 0, 0, 0);
            __builtin_amdgcn_s_setprio(0);
            if (kk == 0) __builtin_amdgcn_s_barrier();  // phase lockstep
        }
        asm volatile("s_waitcnt lgkmcnt(0)" ::: "memory");  // own reads done before next stage
        __builtin_amdgcn_s_barrier();
    }
    // epilogue
#pragma unroll
    for (int i = 0; i < 4; ++i)
#pragma unroll
        for (int j = 0; j < 4; ++j) {
            int col  = n0 + wn * 64 + j * 16 + l15;
            int rowb = m0 + wm * 64 + i * 16 + l4 * 4;
#pragma unroll
            for (int r = 0; r < 4; ++r) {
                if (BF16OUT)
                    ((u16*)Cout)[(size_t)(rowb + r) * N + col] = f2b(acc[i][j][r]);
                else
                    ((float*)Cout)[(size_t)(rowb + r) * N + col] = acc[i][j][r];
            }
        }
}

// ---------------- Flash attention v3: balanced tile pairs ----------------
// 1024 causal tiles (32 qt x 32 h), QBLK=64 (4 waves x 16 rows), KVBLK=64.
// Block b handles tiles (31-p, p) of head h => every block = 33-34 steps.
__global__ __launch_bounds__(256) void attn3(const u16* __restrict__ QKV,
                                             const u16* __restrict__ Vt,
                                             u16* __restrict__ O) {
    __shared__ u16 Ksm[2][64 * 128];  // [kv][d-chunk swz]
    __shared__ u16 Vsm[2][128 * 64];  // [d][kv-chunk swz]
    __shared__ u16 Psm[4][16 * 64];   // per-wave P tile, swz
    const int orig = blockIdx.x;
    const int swz = (orig & 7) * 64 + (orig >> 3);   // 512 = 8*64, bijective
    const int h = swz >> 4, p = swz & 15;
    const int hk = h >> 2;
    const int tid = threadIdx.x, wave = tid >> 6, lane = tid & 63;
    const int l15 = lane & 15, l4 = lane >> 4;
    const u16* Qp = QKV + h * 128;
    const u16* Kp = QKV + 4096 + hk * 128;
    const u16* Vp = Vt + (size_t)hk * (128 * 2048);

    auto stage = [&](int kb, int b) {
#pragma unroll
        for (int it = 0; it < 4; ++it) {
            int L = it * 256 + tid;
            int krow = L >> 4, kslot = L & 15;
            int kcs = (kslot & 8) | ((kslot ^ krow) & 7);
            gload16(Kp + (size_t)(kb * 64 + krow) * NQKV + kcs * 8, &Ksm[b][L * 8]);
            int vrow = L >> 3, vslot = L & 7;
            int vcs = (vslot ^ vrow) & 7;
            gload16(Vp + (size_t)vrow * 2048 + kb * 64 + vcs * 8, &Vsm[b][L * 8]);
        }
    };

#pragma unroll 1
    for (int pass = 0; pass < 2; ++pass) {
        const int qt = pass ? p : 31 - p;
        const int qr0 = qt * 64 + wave * 16;
        const int nkb = qt + 1;

        bf16x8 qf[4];
        {
            const u16* qrow = Qp + (size_t)(qr0 + l15) * NQKV;
#pragma unroll
            for (int c = 0; c < 4; ++c)
                qf[c] = *(const bf16x8*)(qrow + c * 32 + l4 * 8);
        }
        float mrow[4], lsum[4];
#pragma unroll
        for (int r = 0; r < 4; ++r) { mrow[r] = -1e30f; lsum[r] = 0.f; }
        f32x4 o[8] = {};

        stage(0, 0);
#pragma unroll 1
        for (int kb = 0; kb < nkb; ++kb) {
            const int cur = kb & 1;
            if (kb + 1 < nkb) {
                stage(kb + 1, cur ^ 1);
                asm volatile("s_waitcnt vmcnt(8)" ::: "memory");
            } else {
                asm volatile("s_waitcnt vmcnt(0)" ::: "memory");
            }
            __builtin_amdgcn_s_barrier();

            if (kb * 64 <= qr0 + 15) {  // wave has unmasked work
                const u16* Kb_ = Ksm[cur];
                const u16* Vb_ = Vsm[cur];
                const bool diag = (kb * 64 + 63 > qr0);
                // ---- S = Q K^T (log2 domain) ----
                f32x4 sc[4] = {};
#pragma unroll
                for (int f = 0; f < 4; ++f) {
                    const int kv = f * 16 + l15;
#pragma unroll
                    for (int c = 0; c < 4; ++c) {
                        int cd = c * 4 + l4;
                        int cpos = (cd & 8) | ((cd ^ kv) & 7);
                        bf16x8 kf = *(const bf16x8*)(Kb_ + kv * 128 + cpos * 8);
                        sc[f] = __builtin_amdgcn_mfma_f32_16x16x32_bf16(qf[c], kf, sc[f], 0, 0, 0);
                    }
                }
                if (diag) {
#pragma unroll
                    for (int f = 0; f < 4; ++f) {
                        int col = kb * 64 + f * 16 + l15;
#pragma unroll
                        for (int r = 0; r < 4; ++r) {
                            int row = qr0 + l4 * 4 + r;
                            if (col > row) sc[f][r] = -1e30f;
                        }
                    }
                }
                float bm[4];
#pragma unroll
                for (int r = 0; r < 4; ++r)
                    bm[r] = fmaxf(fmaxf(sc[0][r], sc[1][r]), fmaxf(sc[2][r], sc[3][r]));
#pragma unroll
                for (int msk = 1; msk < 16; msk <<= 1)
#pragma unroll
                    for (int r = 0; r < 4; ++r) bm[r] = fmaxf(bm[r], __shfl_xor(bm[r], msk));

                bool need = false;
#pragma unroll
                for (int r = 0; r < 4; ++r) need = need || (bm[r] > mrow[r] + 8.0f);
                if (__any((int)need)) {  // T13 defer-rescale, per-row alpha
                    float al[4];
#pragma unroll
                    for (int r = 0; r < 4; ++r) {
                        float mn = fmaxf(mrow[r], bm[r]);
                        al[r] = exp2fast(mrow[r] - mn);
                        mrow[r] = mn;
                        lsum[r] *= al[r];
                    }
#pragma unroll
                    for (int n = 0; n < 8; ++n)
#pragma unroll
                        for (int r = 0; r < 4; ++r) o[n][r] *= al[r];
                }
                float rs[4] = {0.f, 0.f, 0.f, 0.f};
#pragma unroll
                for (int f = 0; f < 4; ++f) {
#pragma unroll
                    for (int r = 0; r < 4; ++r) {
                        float pw = exp2fast(sc[f][r] - mrow[r]);
                        rs[r] += pw;
                        int q = l4 * 4 + r;
                        int kvc = f * 2 + (l15 >> 3);
                        int slot = (kvc ^ q) & 7;
                        Psm[wave][q * 64 + slot * 8 + (l15 & 7)] = f2b(pw);
                    }
                }
#pragma unroll
                for (int msk = 1; msk < 16; msk <<= 1)
#pragma unroll
                    for (int r = 0; r < 4; ++r) rs[r] += __shfl_xor(rs[r], msk);
#pragma unroll
                for (int r = 0; r < 4; ++r) lsum[r] += rs[r];

                asm volatile("s_waitcnt lgkmcnt(0)" ::: "memory");
                bf16x8 pf[2];
#pragma unroll
                for (int c = 0; c < 2; ++c) {
                    int chc = c * 4 + l4;
                    int slot = (chc ^ l15) & 7;
                    pf[c] = *(const bf16x8*)(&Psm[wave][l15 * 64 + slot * 8]);
                }
#pragma unroll
                for (int n = 0; n < 8; ++n) {
                    int d = n * 16 + l15;
                    bf16x8 vf[2];
#pragma unroll
                    for (int c = 0; c < 2; ++c) {
                        int ch = c * 4 + l4;
                        int slot = (ch ^ d) & 7;
                        vf[c] = *(const bf16x8*)(Vb_ + d * 64 + slot * 8);
                    }
#pragma unroll
                    for (int c = 0; c < 2; ++c)
                        o[n] = __builtin_amdgcn_mfma_f32_16x16x32_bf16(pf[c], vf[c], o[n], 0, 0, 0);
                }
            }  // active
            asm volatile("s_waitcnt lgkmcnt(0)" ::: "memory");
            __builtin_amdgcn_s_barrier();
        }

        // epilogue: O = acc / l
        float inv[4];
#pragma unroll
        for (int r = 0; r < 4; ++r) inv[r] = 1.0f / lsum[r];
#pragma unroll
        for (int n = 0; n < 8; ++n)
#pragma unroll
            for (int r = 0; r < 4; ++r) {
                int row = qr0 + l4 * 4 + r;
                O[(size_t)row * 4096 + h * 128 + n * 16 + l15] = f2b(o[n][r] * inv[r]);
            }
    }  // pass
}

// ---------------- launch ----------------
extern "C" void kernel_launch(void* const* d_in, const int* in_sizes, int n_in,
                              void* d_out, int out_size, void* d_ws, size_t ws_size,
                              hipStream_t stream) {
    const int*   pos = (const int*)d_in[0];
    const float* X   = (const float*)d_in[1];
    const float* Wq  = (const float*)d_in[2];
    const float* Wk  = (const float*)d_in[3];
    const float* Wv  = (const float*)d_in[4];
    const float* Wo  = (const float*)d_in[5];
    float* out = (float*)d_out;

    char* w = (char*)d_ws;
    u16* Xb    = (u16*)(w + 0);          //  16.78 MB
    u16* Wqkvt = (u16*)(w + 16777216);   //  50.33 MB [6144][4096]
    u16* Wot   = (u16*)(w + 67108864);   //  33.55 MB
    u16* QKV   = (u16*)(w + 100663296);  //  25.17 MB [2048][6144]
    u16* Vtb   = (u16*)(w + 125829120);  //   4.19 MB [8][128][2048]
    u16* Ob    = (u16*)(w + 130023424);  //  16.78 MB

    const float SC2 = 0.08838834764831845f * 1.4426950408889634f;  // 1/sqrt(128) * log2(e)

    // conversions / weight transposes (QKV weights packed into one [6144][4096])
    cvt_x<<<4096, 256, 0, stream>>>(X, Xb, S * D / 8);
    tconv<<<dim3(64, 64), 256, 0, stream>>>(Wq, Wqkvt, 4096, 4096);
    tconv<<<dim3(16, 64), 256, 0, stream>>>(Wk, Wqkvt + (size_t)4096 * 4096, 4096, 1024);
    tconv<<<dim3(16, 64), 256, 0, stream>>>(Wv, Wqkvt + (size_t)5120 * 4096, 4096, 1024);
    tconv<<<dim3(64, 64), 256, 0, stream>>>(Wo, Wot, 4096, 4096);

    // fused QKV projection: [2048][6144] — 16 x 24 = 384 blocks
    gemm8<true><<<384, 512, 0, stream>>>(Xb, Wqkvt, QKV, NQKV, 4096, 24);

    // rope (scale*log2e folded into Q)
    rope2<32><<<16384, 256, 0, stream>>>(QKV, pos, SC2);
    rope2<8><<<4096, 256, 0, stream>>>(QKV + 4096, pos, 1.0f);

    // V transpose
    vtrans<<<dim3(32, 2, 8), 256, 0, stream>>>(QKV, Vtb);

    // attention (balanced pairs)
    attn3<<<512, 256, 0, stream>>>(QKV, Vtb, Ob);

    // output projection (f32 out) — 16 x 16 = 256 blocks
    gemm8<false><<<256, 512, 0, stream>>>(Ob, Wot, out, 4096, 4096, 16);
}

// Round 7
// 389.773 us; speedup vs baseline: 1.1055x; 1.1055x over previous
//
#include <hip/hip_runtime.h>

typedef unsigned short u16;
typedef short bf16x8 __attribute__((ext_vector_type(8)));
typedef float f32x4 __attribute__((ext_vector_type(4)));

#define GLB __attribute__((address_space(1)))
#define LDSAS __attribute__((address_space(3)))

constexpr int S = 2048, D = 4096, NH = 32, NHK = 8, DHD = 128;
constexpr int NQKV = 6144;  // 4096 q + 1024 k + 1024 v

__device__ __forceinline__ u16 f2b(float f) {
    union { float f; unsigned u; } v; v.f = f;
    return (u16)((v.u + 0x7fffu + ((v.u >> 16) & 1u)) >> 16);
}
__device__ __forceinline__ float b2f(u16 b) {
    union { unsigned u; float f; } v; v.u = ((unsigned)b) << 16;
    return v.f;
}
__device__ __forceinline__ void gload16(const void* g, void* l) {
    __builtin_amdgcn_global_load_lds((const GLB unsigned int*)g,
                                     (LDSAS unsigned int*)l, 16, 0, 0);
}
#if __has_builtin(__builtin_amdgcn_exp2f)
__device__ __forceinline__ float exp2fast(float x) { return __builtin_amdgcn_exp2f(x); }
#else
__device__ __forceinline__ float exp2fast(float x) { return __expf(0.6931471805599453f * x); }
#endif

// Accurate sin/cos for large args: reduce to revolutions in [0,1), then v_sin/v_cos.
__device__ __forceinline__ void sincos_big(float ang, float* sn, float* cs) {
#if __has_builtin(__builtin_amdgcn_sinf) && __has_builtin(__builtin_amdgcn_cosf)
    float rev = ang * 0.15915494309189535f;  // 1/(2*pi)
    rev = rev - floorf(rev);                 // [0,1)
    *sn = __builtin_amdgcn_sinf(rev);
    *cs = __builtin_amdgcn_cosf(rev);
#else
    *sn = sinf(ang);
    *cs = cosf(ang);
#endif
}

// ---------------- f32 -> bf16 elementwise (8/thread) ----------------
__global__ __launch_bounds__(256) void cvt_x(const float* __restrict__ in,
                                             u16* __restrict__ out, int n8) {
    int i = blockIdx.x * 256 + threadIdx.x;
    if (i >= n8) return;
    const float4* p = (const float4*)in + (size_t)i * 2;
    float4 a = p[0], b = p[1];
    uint4 o;
    o.x = f2b(a.x) | ((unsigned)f2b(a.y) << 16);
    o.y = f2b(a.z) | ((unsigned)f2b(a.w) << 16);
    o.z = f2b(b.x) | ((unsigned)f2b(b.y) << 16);
    o.w = f2b(b.z) | ((unsigned)f2b(b.w) << 16);
    *(uint4*)(out + (size_t)i * 8) = o;
}

// ---------------- f32 [R][C] -> bf16 [C][R] ----------------
__global__ __launch_bounds__(256) void tconv(const float* __restrict__ in,
                                             u16* __restrict__ out, int R, int C) {
    __shared__ float t[64][65];
    int r0 = blockIdx.y * 64, c0 = blockIdx.x * 64;
    int tx = threadIdx.x & 63, ty = threadIdx.x >> 6;
#pragma unroll
    for (int i = 0; i < 64; i += 4)
        t[ty + i][tx] = in[(size_t)(r0 + ty + i) * C + c0 + tx];
    __syncthreads();
#pragma unroll
    for (int i = 0; i < 64; i += 4)
        out[(size_t)(c0 + ty + i) * R + r0 + tx] = f2b(t[tx][ty + i]);
}

// ---------------- bf16 V (QKV cols 5120..6143) -> Vt [hk][d][s] ----------------
__global__ __launch_bounds__(256) void vtrans(const u16* __restrict__ QKV,
                                              u16* __restrict__ Vt) {
    __shared__ u16 t[64][65];
    int hk = blockIdx.z;
    int s0 = blockIdx.x * 64, d0 = blockIdx.y * 64;
    int tx = threadIdx.x & 63, ty = threadIdx.x >> 6;
#pragma unroll
    for (int i = 0; i < 64; i += 4)
        t[ty + i][tx] = QKV[(size_t)(s0 + ty + i) * NQKV + 5120 + hk * 128 + d0 + tx];
    __syncthreads();
#pragma unroll
    for (int i = 0; i < 64; i += 4)
        Vt[(size_t)hk * (128 * 2048) + (size_t)(d0 + ty + i) * 2048 + s0 + tx] = t[tx][ty + i];
}

// ---------------- RoPE in place, bf16, stride NQKV; scale folded in ----------------
template <int NHEADS>
__global__ __launch_bounds__(256) void rope2(u16* __restrict__ T,
                                             const int* __restrict__ pos, float scale) {
    int idx = blockIdx.x * 256 + threadIdx.x;
    int d = idx & 63;
    int h = (idx >> 6) & (NHEADS - 1);
    int s = idx >> (6 + (NHEADS == 32 ? 5 : 3));
    float p = (float)pos[s];
    float inv = __expf(-(float)d * 0.14391156531310576f);  // 10000^(-d/64)
    float ang = p * inv;
    float sn, cs;
    sincos_big(ang, &sn, &cs);
    size_t base = (size_t)s * NQKV + h * 128 + d;
    float x1 = b2f(T[base]), x2 = b2f(T[base + 64]);
    T[base]      = f2b((x1 * cs - x2 * sn) * scale);
    T[base + 64] = f2b((x2 * cs + x1 * sn) * scale);
}

// ---------------- GEMM 256x256: m201-style 4-phase/K-tile pipeline ----------------
// BK=64, 8 waves (2m x 4n, 128x64 C each), dbuf LDS 128KB, T2 chunk-XOR swizzle,
// phase = {ds_read subtile | stage half-tile -> barrier -> lgkmcnt0 -> 16 MFMA -> barrier},
// fragments held across phases (no LDS re-reads), vmcnt(0) only at tile boundary
// (stages front-loaded in phases 0-1 so the drain covers issue-to-use >= 2 phases).
template <bool BF16OUT>
__global__ __launch_bounds__(512, 2) void gemm256(const u16* __restrict__ A,
                                                  const u16* __restrict__ Bt,
                                                  void* __restrict__ Cout,
                                                  int N, int K, int nbx) {
    __shared__ u16 Asm[2][256 * 64];  // 64 KB
    __shared__ u16 Bsm[2][256 * 64];  // 64 KB
    const int cpx = (int)gridDim.x >> 3;
    const int b = ((int)blockIdx.x & 7) * cpx + ((int)blockIdx.x >> 3);
    const int by = b / nbx, bx = b - by * nbx;
    const int m0 = by * 256, n0 = bx * 256;
    const int tid = threadIdx.x;
    const int lane = tid & 63, wave = tid >> 6;
    const int l15 = lane & 15, l4 = lane >> 4;
    const int wm = wave >> 2, wn = wave & 3;  // 2 x 4 waves, each owns 128x64 of C
    f32x4 acc[8][4] = {};

    auto stageA = [&](int t, int buf, int h) {
#pragma unroll
        for (int u = 0; u < 2; ++u) {
            int s = u * 512 + tid;
            int row = s >> 3;
            int cs = (s & 7) ^ (row & 7);
            gload16(A + (size_t)(m0 + h * 128 + row) * K + t * 64 + cs * 8,
                    &Asm[buf][h * 8192 + s * 8]);
        }
    };
    auto stageB = [&](int t, int buf, int h) {
#pragma unroll
        for (int u = 0; u < 2; ++u) {
            int s = u * 512 + tid;
            int row = s >> 3;
            int cs = (s & 7) ^ (row & 7);
            gload16(Bt + (size_t)(n0 + h * 128 + row) * K + t * 64 + cs * 8,
                    &Bsm[buf][h * 8192 + s * 8]);
        }
    };

    const int NT = K >> 6;
    stageA(0, 0, 0); stageA(0, 0, 1); stageB(0, 0, 0); stageB(0, 0, 1);
    asm volatile("s_waitcnt vmcnt(0)" ::: "memory");
    __builtin_amdgcn_s_barrier();

    bf16x8 af[4][2], bf0[2][2], bf1[2][2];
#pragma unroll 1
    for (int t = 0; t < NT; ++t) {
        const int c = t & 1;
        const bool pre = (t + 1 < NT);
        // ---- phase 0: read A(mf0-3) + B(nf0-1); stage next-A ----
#pragma unroll
        for (int i = 0; i < 4; ++i)
#pragma unroll
            for (int kk = 0; kk < 2; ++kk) {
                int row = wm * 128 + i * 16 + l15;
                int cc = (kk * 4 + l4) ^ (row & 7);
                af[i][kk] = *(const bf16x8*)(&Asm[c][row * 64 + cc * 8]);
            }
#pragma unroll
        for (int j = 0; j < 2; ++j)
#pragma unroll
            for (int kk = 0; kk < 2; ++kk) {
                int row = wn * 64 + j * 16 + l15;
                int cc = (kk * 4 + l4) ^ (row & 7);
                bf0[j][kk] = *(const bf16x8*)(&Bsm[c][row * 64 + cc * 8]);
            }
        if (pre) { stageA(t + 1, c ^ 1, 0); stageA(t + 1, c ^ 1, 1); }
        __builtin_amdgcn_s_barrier();
        asm volatile("s_waitcnt lgkmcnt(0)" ::: "memory");
        __builtin_amdgcn_s_setprio(1);
#pragma unroll
        for (int i = 0; i < 4; ++i)
#pragma unroll
            for (int j = 0; j < 2; ++j)
#pragma unroll
                for (int kk = 0; kk < 2; ++kk)
                    acc[i][j] = __builtin_amdgcn_mfma_f32_16x16x32_bf16(af[i][kk], bf0[j][kk], acc[i][j], 0, 0, 0);
        __builtin_amdgcn_s_setprio(0);
        __builtin_amdgcn_s_barrier();
        // ---- phase 1: read B(nf2-3); stage next-B ----
#pragma unroll
        for (int j = 0; j < 2; ++j)
#pragma unroll
            for (int kk = 0; kk < 2; ++kk) {
                int row = wn * 64 + (j + 2) * 16 + l15;
                int cc = (kk * 4 + l4) ^ (row & 7);
                bf1[j][kk] = *(const bf16x8*)(&Bsm[c][row * 64 + cc * 8]);
            }
        if (pre) { stageB(t + 1, c ^ 1, 0); stageB(t + 1, c ^ 1, 1); }
        __builtin_amdgcn_s_barrier();
        asm volatile("s_waitcnt lgkmcnt(0)" ::: "memory");
        __builtin_amdgcn_s_setprio(1);
#pragma unroll
        for (int i = 0; i < 4; ++i)
#pragma unroll
            for (int j = 0; j < 2; ++j)
#pragma unroll
                for (int kk = 0; kk < 2; ++kk)
                    acc[i][j + 2] = __builtin_amdgcn_mfma_f32_16x16x32_bf16(af[i][kk], bf1[j][kk], acc[i][j + 2], 0, 0, 0);
        __builtin_amdgcn_s_setprio(0);
        __builtin_amdgcn_s_barrier();
        // ---- phase 2: read A(mf4-7), overwrite af; B0 held ----
#pragma unroll
        for (int i = 0; i < 4; ++i)
#pragma unroll
            for (int kk = 0; kk < 2; ++kk) {
                int row = wm * 128 + (i + 4) * 16 + l15;
                int cc = (kk * 4 + l4) ^ (row & 7);
                af[i][kk] = *(const bf16x8*)(&Asm[c][row * 64 + cc * 8]);
            }
        __builtin_amdgcn_s_barrier();
        asm volatile("s_waitcnt lgkmcnt(0)" ::: "memory");
        __builtin_amdgcn_s_setprio(1);
#pragma unroll
        for (int i = 0; i < 4; ++i)
#pragma unroll
            for (int j = 0; j < 2; ++j)
#pragma unroll
                for (int kk = 0; kk < 2; ++kk)
                    acc[i + 4][j] = __builtin_amdgcn_mfma_f32_16x16x32_bf16(af[i][kk], bf0[j][kk], acc[i + 4][j], 0, 0, 0);
        __builtin_amdgcn_s_setprio(0);
        __builtin_amdgcn_s_barrier();
        // ---- phase 3: no reads (af, bf1 held); drain stages at tile boundary ----
        __builtin_amdgcn_s_setprio(1);
#pragma unroll
        for (int i = 0; i < 4; ++i)
#pragma unroll
            for (int j = 0; j < 2; ++j)
#pragma unroll
                for (int kk = 0; kk < 2; ++kk)
                    acc[i + 4][j + 2] = __builtin_amdgcn_mfma_f32_16x16x32_bf16(af[i][kk], bf1[j][kk], acc[i + 4][j + 2], 0, 0, 0);
        __builtin_amdgcn_s_setprio(0);
        asm volatile("s_waitcnt vmcnt(0)" ::: "memory");
        __builtin_amdgcn_s_barrier();
    }
    // epilogue
#pragma unroll
    for (int i = 0; i < 8; ++i)
#pragma unroll
        for (int j = 0; j < 4; ++j) {
            int col  = n0 + wn * 64 + j * 16 + l15;
            int rowb = m0 + wm * 128 + i * 16 + l4 * 4;
#pragma unroll
            for (int r = 0; r < 4; ++r) {
                if (BF16OUT)
                    ((u16*)Cout)[(size_t)(rowb + r) * N + col] = f2b(acc[i][j][r]);
                else
                    ((float*)Cout)[(size_t)(rowb + r) * N + col] = acc[i][j][r];
            }
        }
}

// ---------------- Flash attention v3: balanced tile pairs ----------------
// 1024 causal tiles (32 qt x 32 h), QBLK=64 (4 waves x 16 rows), KVBLK=64.
// Block b handles tiles (31-p, p) of head h => every block = 33-34 steps.
__global__ __launch_bounds__(256) void attn3(const u16* __restrict__ QKV,
                                             const u16* __restrict__ Vt,
                                             u16* __restrict__ O) {
    __shared__ u16 Ksm[2][64 * 128];  // [kv][d-chunk swz]
    __shared__ u16 Vsm[2][128 * 64];  // [d][kv-chunk swz]
    __shared__ u16 Psm[4][16 * 64];   // per-wave P tile, swz
    const int orig = blockIdx.x;
    const int swz = (orig & 7) * 64 + (orig >> 3);   // 512 = 8*64, bijective
    const int h = swz >> 4, p = swz & 15;
    const int hk = h >> 2;
    const int tid = threadIdx.x, wave = tid >> 6, lane = tid & 63;
    const int l15 = lane & 15, l4 = lane >> 4;
    const u16* Qp = QKV + h * 128;
    const u16* Kp = QKV + 4096 + hk * 128;
    const u16* Vp = Vt + (size_t)hk * (128 * 2048);

    auto stage = [&](int kb, int b) {
#pragma unroll
        for (int it = 0; it < 4; ++it) {
            int L = it * 256 + tid;
            int krow = L >> 4, kslot = L & 15;
            int kcs = (kslot & 8) | ((kslot ^ krow) & 7);
            gload16(Kp + (size_t)(kb * 64 + krow) * NQKV + kcs * 8, &Ksm[b][L * 8]);
            int vrow = L >> 3, vslot = L & 7;
            int vcs = (vslot ^ vrow) & 7;
            gload16(Vp + (size_t)vrow * 2048 + kb * 64 + vcs * 8, &Vsm[b][L * 8]);
        }
    };

#pragma unroll 1
    for (int pass = 0; pass < 2; ++pass) {
        const int qt = pass ? p : 31 - p;
        const int qr0 = qt * 64 + wave * 16;
        const int nkb = qt + 1;

        bf16x8 qf[4];
        {
            const u16* qrow = Qp + (size_t)(qr0 + l15) * NQKV;
#pragma unroll
            for (int c = 0; c < 4; ++c)
                qf[c] = *(const bf16x8*)(qrow + c * 32 + l4 * 8);
        }
        float mrow[4], lsum[4];
#pragma unroll
        for (int r = 0; r < 4; ++r) { mrow[r] = -1e30f; lsum[r] = 0.f; }
        f32x4 o[8] = {};

        stage(0, 0);
#pragma unroll 1
        for (int kb = 0; kb < nkb; ++kb) {
            const int cur = kb & 1;
            if (kb + 1 < nkb) {
                stage(kb + 1, cur ^ 1);
                asm volatile("s_waitcnt vmcnt(8)" ::: "memory");
            } else {
                asm volatile("s_waitcnt vmcnt(0)" ::: "memory");
            }
            __builtin_amdgcn_s_barrier();

            if (kb * 64 <= qr0 + 15) {  // wave has unmasked work
                const u16* Kb_ = Ksm[cur];
                const u16* Vb_ = Vsm[cur];
                const bool diag = (kb * 64 + 63 > qr0);
                // ---- S = Q K^T (log2 domain) ----
                f32x4 sc[4] = {};
#pragma unroll
                for (int f = 0; f < 4; ++f) {
                    const int kv = f * 16 + l15;
#pragma unroll
                    for (int c = 0; c < 4; ++c) {
                        int cd = c * 4 + l4;
                        int cpos = (cd & 8) | ((cd ^ kv) & 7);
                        bf16x8 kf = *(const bf16x8*)(Kb_ + kv * 128 + cpos * 8);
                        sc[f] = __builtin_amdgcn_mfma_f32_16x16x32_bf16(qf[c], kf, sc[f], 0, 0, 0);
                    }
                }
                if (diag) {
#pragma unroll
                    for (int f = 0; f < 4; ++f) {
                        int col = kb * 64 + f * 16 + l15;
#pragma unroll
                        for (int r = 0; r < 4; ++r) {
                            int row = qr0 + l4 * 4 + r;
                            if (col > row) sc[f][r] = -1e30f;
                        }
                    }
                }
                float bm[4];
#pragma unroll
                for (int r = 0; r < 4; ++r)
                    bm[r] = fmaxf(fmaxf(sc[0][r], sc[1][r]), fmaxf(sc[2][r], sc[3][r]));
#pragma unroll
                for (int msk = 1; msk < 16; msk <<= 1)
#pragma unroll
                    for (int r = 0; r < 4; ++r) bm[r] = fmaxf(bm[r], __shfl_xor(bm[r], msk));

                bool need = false;
#pragma unroll
                for (int r = 0; r < 4; ++r) need = need || (bm[r] > mrow[r] + 8.0f);
                if (__any((int)need)) {  // T13 defer-rescale, per-row alpha
                    float al[4];
#pragma unroll
                    for (int r = 0; r < 4; ++r) {
                        float mn = fmaxf(mrow[r], bm[r]);
                        al[r] = exp2fast(mrow[r] - mn);
                        mrow[r] = mn;
                        lsum[r] *= al[r];
                    }
#pragma unroll
                    for (int n = 0; n < 8; ++n)
#pragma unroll
                        for (int r = 0; r < 4; ++r) o[n][r] *= al[r];
                }
                float rs[4] = {0.f, 0.f, 0.f, 0.f};
#pragma unroll
                for (int f = 0; f < 4; ++f) {
#pragma unroll
                    for (int r = 0; r < 4; ++r) {
                        float pw = exp2fast(sc[f][r] - mrow[r]);
                        rs[r] += pw;
                        int q = l4 * 4 + r;
                        int kvc = f * 2 + (l15 >> 3);
                        int slot = (kvc ^ q) & 7;
                        Psm[wave][q * 64 + slot * 8 + (l15 & 7)] = f2b(pw);
                    }
                }
#pragma unroll
                for (int msk = 1; msk < 16; msk <<= 1)
#pragma unroll
                    for (int r = 0; r < 4; ++r) rs[r] += __shfl_xor(rs[r], msk);
#pragma unroll
                for (int r = 0; r < 4; ++r) lsum[r] += rs[r];

                asm volatile("s_waitcnt lgkmcnt(0)" ::: "memory");
                bf16x8 pf[2];
#pragma unroll
                for (int c = 0; c < 2; ++c) {
                    int chc = c * 4 + l4;
                    int slot = (chc ^ l15) & 7;
                    pf[c] = *(const bf16x8*)(&Psm[wave][l15 * 64 + slot * 8]);
                }
#pragma unroll
                for (int n = 0; n < 8; ++n) {
                    int d = n * 16 + l15;
                    bf16x8 vf[2];
#pragma unroll
                    for (int c = 0; c < 2; ++c) {
                        int ch = c * 4 + l4;
                        int slot = (ch ^ d) & 7;
                        vf[c] = *(const bf16x8*)(Vb_ + d * 64 + slot * 8);
                    }
#pragma unroll
                    for (int c = 0; c < 2; ++c)
                        o[n] = __builtin_amdgcn_mfma_f32_16x16x32_bf16(pf[c], vf[c], o[n], 0, 0, 0);
                }
            }  // active
            asm volatile("s_waitcnt lgkmcnt(0)" ::: "memory");
            __builtin_amdgcn_s_barrier();
        }

        // epilogue: O = acc / l
        float inv[4];
#pragma unroll
        for (int r = 0; r < 4; ++r) inv[r] = 1.0f / lsum[r];
#pragma unroll
        for (int n = 0; n < 8; ++n)
#pragma unroll
            for (int r = 0; r < 4; ++r) {
                int row = qr0 + l4 * 4 + r;
                O[(size_t)row * 4096 + h * 128 + n * 16 + l15] = f2b(o[n][r] * inv[r]);
            }
    }  // pass
}

// ---------------- launch ----------------
extern "C" void kernel_launch(void* const* d_in, const int* in_sizes, int n_in,
                              void* d_out, int out_size, void* d_ws, size_t ws_size,
                              hipStream_t stream) {
    const int*   pos = (const int*)d_in[0];
    const float* X   = (const float*)d_in[1];
    const float* Wq  = (const float*)d_in[2];
    const float* Wk  = (const float*)d_in[3];
    const float* Wv  = (const float*)d_in[4];
    const float* Wo  = (const float*)d_in[5];
    float* out = (float*)d_out;

    char* w = (char*)d_ws;
    u16* Xb    = (u16*)(w + 0);          //  16.78 MB
    u16* Wqkvt = (u16*)(w + 16777216);   //  50.33 MB [6144][4096]
    u16* Wot   = (u16*)(w + 67108864);   //  33.55 MB
    u16* QKV   = (u16*)(w + 100663296);  //  25.17 MB [2048][6144]
    u16* Vtb   = (u16*)(w + 125829120);  //   4.19 MB [8][128][2048]
    u16* Ob    = (u16*)(w + 130023424);  //  16.78 MB

    const float SC2 = 0.08838834764831845f * 1.4426950408889634f;  // 1/sqrt(128) * log2(e)

    // conversions / weight transposes (QKV weights packed into one [6144][4096])
    cvt_x<<<4096, 256, 0, stream>>>(X, Xb, S * D / 8);
    tconv<<<dim3(64, 64), 256, 0, stream>>>(Wq, Wqkvt, 4096, 4096);
    tconv<<<dim3(16, 64), 256, 0, stream>>>(Wk, Wqkvt + (size_t)4096 * 4096, 4096, 1024);
    tconv<<<dim3(16, 64), 256, 0, stream>>>(Wv, Wqkvt + (size_t)5120 * 4096, 4096, 1024);
    tconv<<<dim3(64, 64), 256, 0, stream>>>(Wo, Wot, 4096, 4096);

    // fused QKV projection: [2048][6144] — 8 x 24 = 192 blocks (single round)
    gemm256<true><<<192, 512, 0, stream>>>(Xb, Wqkvt, QKV, NQKV, 4096, 24);

    // rope (scale*log2e folded into Q)
    rope2<32><<<16384, 256, 0, stream>>>(QKV, pos, SC2);
    rope2<8><<<4096, 256, 0, stream>>>(QKV + 4096, pos, 1.0f);

    // V transpose
    vtrans<<<dim3(32, 2, 8), 256, 0, stream>>>(QKV, Vtb);

    // attention (balanced pairs)
    attn3<<<512, 256, 0, stream>>>(QKV, Vtb, Ob);

    // output projection (f32 out) — 8 x 16 = 128 blocks (single round)
    gemm256<false><<<128, 512, 0, stream>>>(Ob, Wot, out, 4096, 4096, 16);
}

// Round 8
// 387.165 us; speedup vs baseline: 1.1129x; 1.0067x over previous
//
#include <hip/hip_runtime.h>

typedef unsigned short u16;
typedef short bf16x8 __attribute__((ext_vector_type(8)));
typedef float f32x4 __attribute__((ext_vector_type(4)));

#define GLB __attribute__((address_space(1)))
#define LDSAS __attribute__((address_space(3)))
#define WAITV(n) asm volatile("s_waitcnt vmcnt(" #n ")" ::: "memory")

constexpr int S = 2048, D = 4096, NH = 32, NHK = 8, DHD = 128;
constexpr int NQKV = 6144;  // 4096 q + 1024 k + 1024 v

__device__ __forceinline__ u16 f2b(float f) {
    union { float f; unsigned u; } v; v.f = f;
    return (u16)((v.u + 0x7fffu + ((v.u >> 16) & 1u)) >> 16);
}
__device__ __forceinline__ float b2f(u16 b) {
    union { unsigned u; float f; } v; v.u = ((unsigned)b) << 16;
    return v.f;
}
__device__ __forceinline__ void gload16(const void* g, void* l) {
    __builtin_amdgcn_global_load_lds((const GLB unsigned int*)g,
                                     (LDSAS unsigned int*)l, 16, 0, 0);
}
#if __has_builtin(__builtin_amdgcn_exp2f)
__device__ __forceinline__ float exp2fast(float x) { return __builtin_amdgcn_exp2f(x); }
#else
__device__ __forceinline__ float exp2fast(float x) { return __expf(0.6931471805599453f * x); }
#endif

// Accurate sin/cos for large args: reduce to revolutions in [0,1), then v_sin/v_cos.
__device__ __forceinline__ void sincos_big(float ang, float* sn, float* cs) {
#if __has_builtin(__builtin_amdgcn_sinf) && __has_builtin(__builtin_amdgcn_cosf)
    float rev = ang * 0.15915494309189535f;  // 1/(2*pi)
    rev = rev - floorf(rev);                 // [0,1)
    *sn = __builtin_amdgcn_sinf(rev);
    *cs = __builtin_amdgcn_cosf(rev);
#else
    *sn = sinf(ang);
    *cs = cosf(ang);
#endif
}

// ---------------- f32 -> bf16 elementwise (8/thread) ----------------
__global__ __launch_bounds__(256) void cvt_x(const float* __restrict__ in,
                                             u16* __restrict__ out, int n8) {
    int i = blockIdx.x * 256 + threadIdx.x;
    if (i >= n8) return;
    const float4* p = (const float4*)in + (size_t)i * 2;
    float4 a = p[0], b = p[1];
    uint4 o;
    o.x = f2b(a.x) | ((unsigned)f2b(a.y) << 16);
    o.y = f2b(a.z) | ((unsigned)f2b(a.w) << 16);
    o.z = f2b(b.x) | ((unsigned)f2b(b.y) << 16);
    o.w = f2b(b.z) | ((unsigned)f2b(b.w) << 16);
    *(uint4*)(out + (size_t)i * 8) = o;
}

// ---------------- f32 [R][C] -> bf16 [C][R] ----------------
__global__ __launch_bounds__(256) void tconv(const float* __restrict__ in,
                                             u16* __restrict__ out, int R, int C) {
    __shared__ float t[64][65];
    int r0 = blockIdx.y * 64, c0 = blockIdx.x * 64;
    int tx = threadIdx.x & 63, ty = threadIdx.x >> 6;
#pragma unroll
    for (int i = 0; i < 64; i += 4)
        t[ty + i][tx] = in[(size_t)(r0 + ty + i) * C + c0 + tx];
    __syncthreads();
#pragma unroll
    for (int i = 0; i < 64; i += 4)
        out[(size_t)(c0 + ty + i) * R + r0 + tx] = f2b(t[tx][ty + i]);
}

// ---------------- bf16 V (QKV cols 5120..6143) -> Vt [hk][d][s] ----------------
__global__ __launch_bounds__(256) void vtrans(const u16* __restrict__ QKV,
                                              u16* __restrict__ Vt) {
    __shared__ u16 t[64][65];
    int hk = blockIdx.z;
    int s0 = blockIdx.x * 64, d0 = blockIdx.y * 64;
    int tx = threadIdx.x & 63, ty = threadIdx.x >> 6;
#pragma unroll
    for (int i = 0; i < 64; i += 4)
        t[ty + i][tx] = QKV[(size_t)(s0 + ty + i) * NQKV + 5120 + hk * 128 + d0 + tx];
    __syncthreads();
#pragma unroll
    for (int i = 0; i < 64; i += 4)
        Vt[(size_t)hk * (128 * 2048) + (size_t)(d0 + ty + i) * 2048 + s0 + tx] = t[tx][ty + i];
}

// ---------------- RoPE in place, bf16, stride NQKV; scale folded in ----------------
template <int NHEADS>
__global__ __launch_bounds__(256) void rope2(u16* __restrict__ T,
                                             const int* __restrict__ pos, float scale) {
    int idx = blockIdx.x * 256 + threadIdx.x;
    int d = idx & 63;
    int h = (idx >> 6) & (NHEADS - 1);
    int s = idx >> (6 + (NHEADS == 32 ? 5 : 3));
    float p = (float)pos[s];
    float inv = __expf(-(float)d * 0.14391156531310576f);  // 10000^(-d/64)
    float ang = p * inv;
    float sn, cs;
    sincos_big(ang, &sn, &cs);
    size_t base = (size_t)s * NQKV + h * 128 + d;
    float x1 = b2f(T[base]), x2 = b2f(T[base + 64]);
    T[base]      = f2b((x1 * cs - x2 * sn) * scale);
    T[base + 64] = f2b((x2 * cs + x1 * sn) * scale);
}

// ---------------- GEMM W: 256xBN tile, BK=64, 8 waves, counted-vmcnt pipeline ----------------
// Stages per K-tile: S0=A-half0 (2 loads), S1=B (LB loads), S2=A-half1 (2 loads).
// Split-m: wave wm owns rows wm*64..+63 (half0) and 128+wm*64..+63 (half1), so
// phase0 consumes only {A0,B}, phase1 only {A1}. Waits are partial (never a full
// mid-loop drain); a wait+barrier pair makes all waves' retired stages visible.
// NBUF=3: stage t+2, ONE wait vmcnt(6+2LB) per tile. NBUF=2: stage t+1, waits vmcnt(4+LB).
template <int BN, int NBUF, bool BF16OUT>
__global__ __launch_bounds__(512, 2) void gemmW(const u16* __restrict__ A,
                                                const u16* __restrict__ Bt,
                                                void* __restrict__ Cout,
                                                int N, int K) {
    constexpr int LB = BN / 64;    // B stage loads per thread
    constexpr int NJ = BN / 64;    // n-frags per wave
    constexpr int WCOL = BN / 4;   // cols per wave
    __shared__ u16 Asm[NBUF][256 * 64];
    __shared__ u16 Bsm[NBUF][BN * 64];
    const int cpx = (int)gridDim.x >> 3;
    const int b = ((int)blockIdx.x & 7) * cpx + ((int)blockIdx.x >> 3);
    const int nbx = N / BN;
    const int by = b / nbx, bx = b - by * nbx;
    const int m0 = by * 256, n0 = bx * BN;
    const int tid = threadIdx.x, lane = tid & 63, wave = tid >> 6;
    const int l15 = lane & 15, l4 = lane >> 4;
    const int wm = wave >> 2, wn = wave & 3;
    f32x4 acc[8][NJ] = {};

    auto stA0 = [&](int t, int buf) {
#pragma unroll
        for (int u = 0; u < 2; ++u) {
            int s = u * 512 + tid;
            int row = s >> 3, cs = (s & 7) ^ (row & 7);
            gload16(A + (size_t)(m0 + row) * K + t * 64 + cs * 8, &Asm[buf][s * 8]);
        }
    };
    auto stB = [&](int t, int buf) {
#pragma unroll
        for (int u = 0; u < LB; ++u) {
            int s = u * 512 + tid;
            int row = s >> 3, cs = (s & 7) ^ (row & 7);
            gload16(Bt + (size_t)(n0 + row) * K + t * 64 + cs * 8, &Bsm[buf][s * 8]);
        }
    };
    auto stA1 = [&](int t, int buf) {
#pragma unroll
        for (int u = 0; u < 2; ++u) {
            int s = u * 512 + tid;
            int row = s >> 3, cs = (s & 7) ^ (row & 7);  // (128+row)&7 == row&7
            gload16(A + (size_t)(m0 + 128 + row) * K + t * 64 + cs * 8,
                    &Asm[buf][128 * 64 + s * 8]);
        }
    };

    const int NT = K >> 6;
    // prologue
    stA0(0, 0); stB(0, 0); stA1(0, 0);
    if constexpr (NBUF == 3) { stA0(1, 1); stB(1, 1); stA1(1, 1); }

    bf16x8 af[4][2], bfr[NJ][2];
#pragma unroll 1
    for (int t = 0; t < NT; ++t) {
        const int cur = (NBUF == 2) ? (t & 1) : (t % 3);
        const int stb = (NBUF == 2) ? (cur ^ 1) : ((cur >= 1) ? cur - 1 : 2);
        const int ts = t + NBUF - 1;
        const bool pre = ts < NT;
        if (pre) { stA0(ts, stb); stB(ts, stb); }
        if constexpr (NBUF == 2) {
            if (pre) { if constexpr (LB == 3) WAITV(7); else WAITV(6); }
            else WAITV(2);
        } else {
            if (pre) { if constexpr (LB == 3) WAITV(12); else WAITV(10); }
            else if (t + 1 < NT) { if constexpr (LB == 3) WAITV(7); else WAITV(6); }
            else WAITV(0);
        }
        __builtin_amdgcn_s_barrier();
        // ---- phase 0: a0 x b ----
#pragma unroll
        for (int i = 0; i < 4; ++i)
#pragma unroll
            for (int kk = 0; kk < 2; ++kk) {
                int row = wm * 64 + i * 16 + l15;
                int cc = (kk * 4 + l4) ^ (row & 7);
                af[i][kk] = *(const bf16x8*)(&Asm[cur][row * 64 + cc * 8]);
            }
#pragma unroll
        for (int j = 0; j < NJ; ++j)
#pragma unroll
            for (int kk = 0; kk < 2; ++kk) {
                int row = wn * WCOL + j * 16 + l15;
                int cc = (kk * 4 + l4) ^ (row & 7);
                bfr[j][kk] = *(const bf16x8*)(&Bsm[cur][row * 64 + cc * 8]);
            }
        __builtin_amdgcn_s_setprio(1);
#pragma unroll
        for (int i = 0; i < 4; ++i)
#pragma unroll
            for (int j = 0; j < NJ; ++j)
#pragma unroll
                for (int kk = 0; kk < 2; ++kk)
                    acc[i][j] = __builtin_amdgcn_mfma_f32_16x16x32_bf16(af[i][kk], bfr[j][kk], acc[i][j], 0, 0, 0);
        __builtin_amdgcn_s_setprio(0);
        // ---- phase 1: a1 x b ----
        if (pre) stA1(ts, stb);
        if constexpr (NBUF == 2) {
            if (pre) { if constexpr (LB == 3) WAITV(7); else WAITV(6); }
            else WAITV(0);
            __builtin_amdgcn_s_barrier();
        }
#pragma unroll
        for (int i = 0; i < 4; ++i)
#pragma unroll
            for (int kk = 0; kk < 2; ++kk) {
                int row = wm * 64 + i * 16 + l15;  // local row within half1
                int cc = (kk * 4 + l4) ^ (row & 7);
                af[i][kk] = *(const bf16x8*)(&Asm[cur][128 * 64 + row * 64 + cc * 8]);
            }
        __builtin_amdgcn_s_setprio(1);
#pragma unroll
        for (int i = 0; i < 4; ++i)
#pragma unroll
            for (int j = 0; j < NJ; ++j)
#pragma unroll
                for (int kk = 0; kk < 2; ++kk)
                    acc[i + 4][j] = __builtin_amdgcn_mfma_f32_16x16x32_bf16(af[i][kk], bfr[j][kk], acc[i + 4][j], 0, 0, 0);
        __builtin_amdgcn_s_setprio(0);
        // buffer-reuse fence: all waves done reading buf cur before next tile stages into it
        asm volatile("s_waitcnt lgkmcnt(0)" ::: "memory");
        __builtin_amdgcn_s_barrier();
    }
    // epilogue
#pragma unroll
    for (int i = 0; i < 8; ++i)
#pragma unroll
        for (int j = 0; j < NJ; ++j) {
            int col = n0 + wn * WCOL + j * 16 + l15;
            int rowb = m0 + (i < 4 ? wm * 64 + i * 16 : 128 + wm * 64 + (i - 4) * 16) + l4 * 4;
#pragma unroll
            for (int r = 0; r < 4; ++r) {
                if (BF16OUT)
                    ((u16*)Cout)[(size_t)(rowb + r) * N + col] = f2b(acc[i][j][r]);
                else
                    ((float*)Cout)[(size_t)(rowb + r) * N + col] = acc[i][j][r];
            }
        }
}

// ---------------- Flash attention v3: balanced tile pairs ----------------
__global__ __launch_bounds__(256) void attn3(const u16* __restrict__ QKV,
                                             const u16* __restrict__ Vt,
                                             u16* __restrict__ O) {
    __shared__ u16 Ksm[2][64 * 128];  // [kv][d-chunk swz]
    __shared__ u16 Vsm[2][128 * 64];  // [d][kv-chunk swz]
    __shared__ u16 Psm[4][16 * 64];   // per-wave P tile, swz
    const int orig = blockIdx.x;
    const int swz = (orig & 7) * 64 + (orig >> 3);   // 512 = 8*64, bijective
    const int h = swz >> 4, p = swz & 15;
    const int hk = h >> 2;
    const int tid = threadIdx.x, wave = tid >> 6, lane = tid & 63;
    const int l15 = lane & 15, l4 = lane >> 4;
    const u16* Qp = QKV + h * 128;
    const u16* Kp = QKV + 4096 + hk * 128;
    const u16* Vp = Vt + (size_t)hk * (128 * 2048);

    auto stage = [&](int kb, int b) {
#pragma unroll
        for (int it = 0; it < 4; ++it) {
            int L = it * 256 + tid;
            int krow = L >> 4, kslot = L & 15;
            int kcs = (kslot & 8) | ((kslot ^ krow) & 7);
            gload16(Kp + (size_t)(kb * 64 + krow) * NQKV + kcs * 8, &Ksm[b][L * 8]);
            int vrow = L >> 3, vslot = L & 7;
            int vcs = (vslot ^ vrow) & 7;
            gload16(Vp + (size_t)vrow * 2048 + kb * 64 + vcs * 8, &Vsm[b][L * 8]);
        }
    };

#pragma unroll 1
    for (int pass = 0; pass < 2; ++pass) {
        const int qt = pass ? p : 31 - p;
        const int qr0 = qt * 64 + wave * 16;
        const int nkb = qt + 1;

        bf16x8 qf[4];
        {
            const u16* qrow = Qp + (size_t)(qr0 + l15) * NQKV;
#pragma unroll
            for (int c = 0; c < 4; ++c)
                qf[c] = *(const bf16x8*)(qrow + c * 32 + l4 * 8);
        }
        float mrow[4], lsum[4];
#pragma unroll
        for (int r = 0; r < 4; ++r) { mrow[r] = -1e30f; lsum[r] = 0.f; }
        f32x4 o[8] = {};

        stage(0, 0);
#pragma unroll 1
        for (int kb = 0; kb < nkb; ++kb) {
            const int cur = kb & 1;
            if (kb + 1 < nkb) {
                stage(kb + 1, cur ^ 1);
                asm volatile("s_waitcnt vmcnt(8)" ::: "memory");
            } else {
                asm volatile("s_waitcnt vmcnt(0)" ::: "memory");
            }
            __builtin_amdgcn_s_barrier();

            if (kb * 64 <= qr0 + 15) {  // wave has unmasked work
                const u16* Kb_ = Ksm[cur];
                const u16* Vb_ = Vsm[cur];
                const bool diag = (kb * 64 + 63 > qr0);
                // ---- S = Q K^T (log2 domain) ----
                f32x4 sc[4] = {};
#pragma unroll
                for (int f = 0; f < 4; ++f) {
                    const int kv = f * 16 + l15;
#pragma unroll
                    for (int c = 0; c < 4; ++c) {
                        int cd = c * 4 + l4;
                        int cpos = (cd & 8) | ((cd ^ kv) & 7);
                        bf16x8 kf = *(const bf16x8*)(Kb_ + kv * 128 + cpos * 8);
                        sc[f] = __builtin_amdgcn_mfma_f32_16x16x32_bf16(qf[c], kf, sc[f], 0, 0, 0);
                    }
                }
                if (diag) {
#pragma unroll
                    for (int f = 0; f < 4; ++f) {
                        int col = kb * 64 + f * 16 + l15;
#pragma unroll
                        for (int r = 0; r < 4; ++r) {
                            int row = qr0 + l4 * 4 + r;
                            if (col > row) sc[f][r] = -1e30f;
                        }
                    }
                }
                float bm[4];
#pragma unroll
                for (int r = 0; r < 4; ++r)
                    bm[r] = fmaxf(fmaxf(sc[0][r], sc[1][r]), fmaxf(sc[2][r], sc[3][r]));
#pragma unroll
                for (int msk = 1; msk < 16; msk <<= 1)
#pragma unroll
                    for (int r = 0; r < 4; ++r) bm[r] = fmaxf(bm[r], __shfl_xor(bm[r], msk));

                bool need = false;
#pragma unroll
                for (int r = 0; r < 4; ++r) need = need || (bm[r] > mrow[r] + 8.0f);
                if (__any((int)need)) {  // T13 defer-rescale, per-row alpha
                    float al[4];
#pragma unroll
                    for (int r = 0; r < 4; ++r) {
                        float mn = fmaxf(mrow[r], bm[r]);
                        al[r] = exp2fast(mrow[r] - mn);
                        mrow[r] = mn;
                        lsum[r] *= al[r];
                    }
#pragma unroll
                    for (int n = 0; n < 8; ++n)
#pragma unroll
                        for (int r = 0; r < 4; ++r) o[n][r] *= al[r];
                }
                float rs[4] = {0.f, 0.f, 0.f, 0.f};
#pragma unroll
                for (int f = 0; f < 4; ++f) {
#pragma unroll
                    for (int r = 0; r < 4; ++r) {
                        float pw = exp2fast(sc[f][r] - mrow[r]);
                        rs[r] += pw;
                        int q = l4 * 4 + r;
                        int kvc = f * 2 + (l15 >> 3);
                        int slot = (kvc ^ q) & 7;
                        Psm[wave][q * 64 + slot * 8 + (l15 & 7)] = f2b(pw);
                    }
                }
#pragma unroll
                for (int msk = 1; msk < 16; msk <<= 1)
#pragma unroll
                    for (int r = 0; r < 4; ++r) rs[r] += __shfl_xor(rs[r], msk);
#pragma unroll
                for (int r = 0; r < 4; ++r) lsum[r] += rs[r];

                asm volatile("s_waitcnt lgkmcnt(0)" ::: "memory");
                bf16x8 pf[2];
#pragma unroll
                for (int c = 0; c < 2; ++c) {
                    int chc = c * 4 + l4;
                    int slot = (chc ^ l15) & 7;
                    pf[c] = *(const bf16x8*)(&Psm[wave][l15 * 64 + slot * 8]);
                }
#pragma unroll
                for (int n = 0; n < 8; ++n) {
                    int d = n * 16 + l15;
                    bf16x8 vf[2];
#pragma unroll
                    for (int c = 0; c < 2; ++c) {
                        int ch = c * 4 + l4;
                        int slot = (ch ^ d) & 7;
                        vf[c] = *(const bf16x8*)(Vb_ + d * 64 + slot * 8);
                    }
#pragma unroll
                    for (int c = 0; c < 2; ++c)
                        o[n] = __builtin_amdgcn_mfma_f32_16x16x32_bf16(pf[c], vf[c], o[n], 0, 0, 0);
                }
            }  // active
            asm volatile("s_waitcnt lgkmcnt(0)" ::: "memory");
            __builtin_amdgcn_s_barrier();
        }

        // epilogue: O = acc / l
        float inv[4];
#pragma unroll
        for (int r = 0; r < 4; ++r) inv[r] = 1.0f / lsum[r];
#pragma unroll
        for (int n = 0; n < 8; ++n)
#pragma unroll
            for (int r = 0; r < 4; ++r) {
                int row = qr0 + l4 * 4 + r;
                O[(size_t)row * 4096 + h * 128 + n * 16 + l15] = f2b(o[n][r] * inv[r]);
            }
    }  // pass
}

// ---------------- launch ----------------
extern "C" void kernel_launch(void* const* d_in, const int* in_sizes, int n_in,
                              void* d_out, int out_size, void* d_ws, size_t ws_size,
                              hipStream_t stream) {
    const int*   pos = (const int*)d_in[0];
    const float* X   = (const float*)d_in[1];
    const float* Wq  = (const float*)d_in[2];
    const float* Wk  = (const float*)d_in[3];
    const float* Wv  = (const float*)d_in[4];
    const float* Wo  = (const float*)d_in[5];
    float* out = (float*)d_out;

    char* w = (char*)d_ws;
    u16* Xb    = (u16*)(w + 0);          //  16.78 MB
    u16* Wqkvt = (u16*)(w + 16777216);   //  50.33 MB [6144][4096]
    u16* Wot   = (u16*)(w + 67108864);   //  33.55 MB
    u16* QKV   = (u16*)(w + 100663296);  //  25.17 MB [2048][6144]
    u16* Vtb   = (u16*)(w + 125829120);  //   4.19 MB [8][128][2048]
    u16* Ob    = (u16*)(w + 130023424);  //  16.78 MB

    const float SC2 = 0.08838834764831845f * 1.4426950408889634f;  // 1/sqrt(128) * log2(e)

    // conversions / weight transposes (QKV weights packed into one [6144][4096])
    cvt_x<<<4096, 256, 0, stream>>>(X, Xb, S * D / 8);
    tconv<<<dim3(64, 64), 256, 0, stream>>>(Wq, Wqkvt, 4096, 4096);
    tconv<<<dim3(16, 64), 256, 0, stream>>>(Wk, Wqkvt + (size_t)4096 * 4096, 4096, 1024);
    tconv<<<dim3(16, 64), 256, 0, stream>>>(Wv, Wqkvt + (size_t)5120 * 4096, 4096, 1024);
    tconv<<<dim3(64, 64), 256, 0, stream>>>(Wo, Wot, 4096, 4096);

    // fused QKV projection: [2048][6144] — 256 blocks exact (8 x 32, BN=192)
    gemmW<192, 2, true><<<256, 512, 0, stream>>>(Xb, Wqkvt, QKV, NQKV, 4096);

    // rope (scale*log2e folded into Q)
    rope2<32><<<16384, 256, 0, stream>>>(QKV, pos, SC2);
    rope2<8><<<4096, 256, 0, stream>>>(QKV + 4096, pos, 1.0f);

    // V transpose
    vtrans<<<dim3(32, 2, 8), 256, 0, stream>>>(QKV, Vtb);

    // attention (balanced pairs)
    attn3<<<512, 256, 0, stream>>>(QKV, Vtb, Ob);

    // output projection (f32 out) — 256 blocks exact (8 x 32, BN=128, triple-buffered)
    gemmW<128, 3, false><<<256, 512, 0, stream>>>(Ob, Wot, out, 4096, 4096);
}